// Round 9
// baseline (73.073 us; speedup 1.0000x reference)
//
#include <hip/hip_runtime.h>

#define HW        128
#define PLANE     16384            // 128*128
#define NCH       64
#define NB        32
#define NQ        4
#define NPART     8192             // fallback partial count
#define COUNT_INV (1.0f / 524288.0f)
#define EPSV      1e-5f
#define GRID_C    512              // coop grid: 512 blocks x 4 planes

#define YELEMS    (NB * NCH * PLANE)
#define PART_OFF  (YELEMS / 2)
#define WS_NEED   ((size_t)YELEMS * 2 + 16384 * 4)

typedef float    f4v  __attribute__((ext_vector_type(4)));
typedef _Float16 h4v  __attribute__((ext_vector_type(4)));
typedef _Float16 h64v __attribute__((ext_vector_type(64)));

__device__ __forceinline__ void load_win(const float* __restrict__ bp, int r0, int w4,
                                         bool hasL, bool hasR, float (&v)[6][6]) {
#pragma unroll
    for (int i = 0; i < 6; ++i) {
        int g = r0 - 1 + i;
        if ((unsigned)g < (unsigned)HW) {
            const float* rp = bp + g * HW + w4;
            float4 m = *(const float4*)rp;
            v[i][0] = hasL ? rp[-1] : 0.f;
            v[i][1] = m.x; v[i][2] = m.y; v[i][3] = m.z; v[i][4] = m.w;
            v[i][5] = hasR ? rp[4] : 0.f;
        } else {
#pragma unroll
            for (int j = 0; j < 6; ++j) v[i][j] = 0.f;
        }
    }
}

__device__ __forceinline__ void conv_row(const float (&tp)[6], const float (&md)[6],
                                         const float (&bt)[6], const float* W,
                                         float bias, float (&acc)[4]) {
#pragma unroll
    for (int j = 0; j < 4; ++j) {
        float a = bias;
        a = fmaf(tp[j],     W[0], a);
        a = fmaf(tp[j + 1], W[1], a);
        a = fmaf(tp[j + 2], W[2], a);
        a = fmaf(md[j],     W[3], a);
        a = fmaf(md[j + 1], W[4], a);
        a = fmaf(md[j + 2], W[5], a);
        a = fmaf(bt[j],     W[6], a);
        a = fmaf(bt[j + 1], W[7], a);
        a = fmaf(bt[j + 2], W[8], a);
        acc[j] = a;
    }
}

// ---------------- fused kernel, y in named vector registers, INLINE grid sync ----
// 512 blocks x 256 threads, __launch_bounds__(256,2) -> 256-VGPR budget.
// Block bid: channel c = bid&63, planes n = (bid>>6)*4 + pi.
// Grid barrier is hand-inlined (device-scope atomic + spin) so NO function call
// exists while y is live -> register allocator can keep y in VGPRs.
// ws floats: [0..2047] per-plane sum (idx c*32+n), [2048..4095] sumsq,
//            [4096] arrival counter (zeroed by hipMemsetAsync each launch).

#define PHASE1(PI, Y)                                                          \
    {                                                                          \
        const int n     = np4 + (PI);                                          \
        const int plane = n * NCH + c;                                         \
        const float* bp = x + (size_t)plane * PLANE;                           \
        float sum = 0.f, sq = 0.f;                                             \
        _Pragma("unroll")                                                      \
        for (int k = 0; k < 4; ++k) {                                          \
            const int r0 = rg * 16 + k * 4;                                    \
            float v[6][6];                                                     \
            load_win(bp, r0, w4, hasL, hasR, v);                               \
            _Pragma("unroll")                                                  \
            for (int rr = 0; rr < 4; ++rr) {                                   \
                float acc[4];                                                  \
                conv_row(v[rr], v[rr + 1], v[rr + 2], W, bv, acc);             \
                Y[k * 16 + rr * 4 + 0] = (_Float16)acc[0];                     \
                Y[k * 16 + rr * 4 + 1] = (_Float16)acc[1];                     \
                Y[k * 16 + rr * 4 + 2] = (_Float16)acc[2];                     \
                Y[k * 16 + rr * 4 + 3] = (_Float16)acc[3];                     \
                _Pragma("unroll")                                              \
                for (int j = 0; j < 4; ++j) {                                  \
                    sum += acc[j];                                             \
                    sq = fmaf(acc[j], acc[j], sq);                             \
                }                                                              \
            }                                                                  \
        }                                                                      \
        _Pragma("unroll")                                                      \
        for (int off = 32; off; off >>= 1) {                                   \
            sum += __shfl_down(sum, off);                                      \
            sq  += __shfl_down(sq, off);                                       \
        }                                                                      \
        if ((t & 63) == 0) { red[t >> 6] = sum; red[4 + (t >> 6)] = sq; }      \
        __syncthreads();                                                       \
        if (t == 0) {                                                          \
            partials[c * 32 + n]        = red[0] + red[1] + red[2] + red[3];   \
            partials[2048 + c * 32 + n] = red[4] + red[5] + red[6] + red[7];   \
        }                                                                      \
        __syncthreads();                                                       \
    }

#define PHASE2(PI, Y)                                                          \
    {                                                                          \
        const int plane = (np4 + (PI)) * NCH + c;                              \
        float* op = out + (size_t)plane * PLANE;                               \
        _Pragma("unroll")                                                      \
        for (int k = 0; k < 4; ++k) {                                          \
            _Pragma("unroll")                                                  \
            for (int rr = 0; rr < 4; ++rr) {                                   \
                f4v o;                                                         \
                o.x = fmaxf(fmaf((float)Y[k * 16 + rr * 4 + 0], s, sh), 0.f);  \
                o.y = fmaxf(fmaf((float)Y[k * 16 + rr * 4 + 1], s, sh), 0.f);  \
                o.z = fmaxf(fmaf((float)Y[k * 16 + rr * 4 + 2], s, sh), 0.f);  \
                o.w = fmaxf(fmaf((float)Y[k * 16 + rr * 4 + 3], s, sh), 0.f);  \
                const int row = rg * 16 + k * 4 + rr;                          \
                __builtin_nontemporal_store(o, (f4v*)(op + row * HW + w4));    \
            }                                                                  \
        }                                                                      \
    }

__global__ __launch_bounds__(256, 2) void fused(const float* __restrict__ x,
                                                const float* __restrict__ wgt,
                                                const float* __restrict__ bias,
                                                const float* __restrict__ gamma,
                                                const float* __restrict__ beta,
                                                float* __restrict__ partials,
                                                unsigned int* __restrict__ cnt,
                                                float* __restrict__ out) {
    __shared__ float red[8];
    __shared__ float ssh[2];
    const int bid = blockIdx.x;        // 0..511
    const int c   = bid & 63;
    const int np4 = (bid >> 6) * 4;    // first n of this block's 4 planes
    const int t   = threadIdx.x;
    const int cg_ = t & 31, rg = t >> 5;
    const int w4  = cg_ * 4;
    const bool hasL = (cg_ != 0), hasR = (cg_ != 31);

    float W[9];
#pragma unroll
    for (int k = 0; k < 9; ++k) W[k] = wgt[c * 9 + k];
    const float bv = bias[c];

    h64v yA, yB, yC, yD;               // 4 planes x 64 px, packed fp16 (32 VGPR each)

    PHASE1(0, yA)
    PHASE1(1, yB)
    PHASE1(2, yC)
    PHASE1(3, yD)

    // ---- inline grid barrier (no call -> y stays in registers) ----
    if (t == 0) {
        __threadfence();               // flush partials device-wide
        __hip_atomic_fetch_add(cnt, 1u, __ATOMIC_ACQ_REL, __HIP_MEMORY_SCOPE_AGENT);
        while (__hip_atomic_load(cnt, __ATOMIC_ACQUIRE, __HIP_MEMORY_SCOPE_AGENT)
               < (unsigned)GRID_C) {
            __builtin_amdgcn_s_sleep(8);
        }
    }
    __syncthreads();

    // ---- stats fold: 32 lanes, coalesced ----
    if (t < 32) {
        float S = partials[c * 32 + t];
        float Q = partials[2048 + c * 32 + t];
#pragma unroll
        for (int off = 16; off; off >>= 1) {
            S += __shfl_xor(S, off);
            Q += __shfl_xor(Q, off);
        }
        if (t == 0) {
            float mean = S * COUNT_INV;
            float var  = fmaxf(Q * COUNT_INV - mean * mean, 0.f);
            float s    = gamma[c] * rsqrtf(var + EPSV);
            ssh[0] = s;
            ssh[1] = beta[c] - mean * s;   // conv bias already inside y
        }
    }
    __syncthreads();
    const float s  = ssh[0];
    const float sh = ssh[1];

    PHASE2(0, yA)
    PHASE2(1, yB)
    PHASE2(2, yC)
    PHASE2(3, yD)
}

// ---------------- fallback: round-5 two-pass (fp16 y staging) ----------------
__global__ __launch_bounds__(256) void pass_conv_stats(const float* __restrict__ x,
                                                       const float* __restrict__ wgt,
                                                       const float* __restrict__ bias,
                                                       _Float16* __restrict__ yh,
                                                       float* __restrict__ partials) {
    __shared__ float red[8];
    const int bid   = blockIdx.x;
    const int q     = bid & 3;
    const int plane = bid >> 2;
    const int c     = plane & 63;
    const int n     = plane >> 6;
    const int t     = threadIdx.x;
    const int cg    = t & 31, rg = t >> 5;
    const int w4    = cg * 4, r0 = q * 32 + rg * 4;
    const bool hasL = (cg != 0), hasR = (cg != 31);

    float W[9];
#pragma unroll
    for (int k = 0; k < 9; ++k) W[k] = wgt[c * 9 + k];
    const float bv = bias[c];
    const float* bp = x + (size_t)plane * PLANE;
    _Float16* yp = yh + (size_t)plane * PLANE;

    float v[6][6];
    load_win(bp, r0, w4, hasL, hasR, v);

    float sum = 0.f, sq = 0.f;
#pragma unroll
    for (int k = 0; k < 4; ++k) {
        float acc[4];
        conv_row(v[k], v[k + 1], v[k + 2], W, bv, acc);
        h4v hv;
        hv.x = (_Float16)acc[0]; hv.y = (_Float16)acc[1];
        hv.z = (_Float16)acc[2]; hv.w = (_Float16)acc[3];
        *(h4v*)(yp + (r0 + k) * HW + w4) = hv;
#pragma unroll
        for (int j = 0; j < 4; ++j) { sum += acc[j]; sq = fmaf(acc[j], acc[j], sq); }
    }
#pragma unroll
    for (int off = 32; off; off >>= 1) {
        sum += __shfl_down(sum, off);
        sq  += __shfl_down(sq, off);
    }
    const int wave = t >> 6, lane = t & 63;
    if (lane == 0) { red[wave] = sum; red[4 + wave] = sq; }
    __syncthreads();
    if (t == 0) {
        const int pi = n * 4 + q;
        partials[c * 128 + pi]         = red[0] + red[1] + red[2] + red[3];
        partials[NPART + c * 128 + pi] = red[4] + red[5] + red[6] + red[7];
    }
}

__global__ __launch_bounds__(256) void pass_norm(const _Float16* __restrict__ yh,
                                                 const float* __restrict__ partials,
                                                 const float* __restrict__ gamma,
                                                 const float* __restrict__ beta,
                                                 float* __restrict__ out) {
    const int bid   = blockIdx.x;
    const int q     = bid & 3;
    const int plane = bid >> 2;
    const int c     = plane & 63;
    const int t     = threadIdx.x;
    const int cg    = t & 31, rg = t >> 5;
    const int w4    = cg * 4, r0 = q * 32 + rg * 4;

    const _Float16* yp = yh + (size_t)plane * PLANE;
    h4v hv[4];
#pragma unroll
    for (int k = 0; k < 4; ++k)
        hv[k] = *(const h4v*)(yp + (r0 + k) * HW + w4);

    const int lane = t & 63;
    float S = partials[c * 128 + lane]         + partials[c * 128 + 64 + lane];
    float Q = partials[NPART + c * 128 + lane] + partials[NPART + c * 128 + 64 + lane];
#pragma unroll
    for (int off = 32; off; off >>= 1) {
        S += __shfl_xor(S, off);
        Q += __shfl_xor(Q, off);
    }
    const float mean = S * COUNT_INV;
    const float var  = fmaxf(Q * COUNT_INV - mean * mean, 0.f);
    const float s    = gamma[c] * rsqrtf(var + EPSV);
    const float sh   = beta[c] - mean * s;

    float* op = out + (size_t)plane * PLANE;
#pragma unroll
    for (int k = 0; k < 4; ++k) {
        f4v o;
        o.x = fmaxf(fmaf((float)hv[k].x, s, sh), 0.f);
        o.y = fmaxf(fmaf((float)hv[k].y, s, sh), 0.f);
        o.z = fmaxf(fmaf((float)hv[k].z, s, sh), 0.f);
        o.w = fmaxf(fmaf((float)hv[k].w, s, sh), 0.f);
        __builtin_nontemporal_store(o, (f4v*)(op + (r0 + k) * HW + w4));
    }
}

extern "C" void kernel_launch(void* const* d_in, const int* in_sizes, int n_in,
                              void* d_out, int out_size, void* d_ws, size_t ws_size,
                              hipStream_t stream) {
    const float* x     = (const float*)d_in[0];
    const float* w     = (const float*)d_in[1];
    const float* b     = (const float*)d_in[2];
    const float* gamma = (const float*)d_in[3];
    const float* beta  = (const float*)d_in[4];
    float* out = (float*)d_out;

    int nb = 0;
    hipError_t qe = hipOccupancyMaxActiveBlocksPerMultiprocessor(
        &nb, reinterpret_cast<const void*>(fused), 256, 0);

    bool coop_ok = false;
    if (qe == hipSuccess && nb >= 2) {
        float* parts      = (float*)d_ws;
        unsigned int* cnt = (unsigned int*)((float*)d_ws + 4096);
        hipMemsetAsync(cnt, 0, sizeof(unsigned int), stream);
        const float* xa = x; const float* wa = w; const float* ba = b;
        const float* ga = gamma; const float* be = beta;
        float* pw = parts; unsigned int* ca = cnt; float* oa = out;
        void* args[] = {&xa, &wa, &ba, &ga, &be, &pw, &ca, &oa};
        hipError_t le = hipLaunchCooperativeKernel(
            reinterpret_cast<const void*>(fused), dim3(GRID_C), dim3(256),
            args, 0, stream);
        coop_ok = (le == hipSuccess);
    }

    if (!coop_ok && ws_size >= WS_NEED) {
        _Float16* yh  = (_Float16*)d_ws;
        float* parts  = (float*)d_ws + PART_OFF;
        pass_conv_stats<<<NB * NCH * NQ, 256, 0, stream>>>(x, w, b, yh, parts);
        pass_norm<<<NB * NCH * NQ, 256, 0, stream>>>(yh, parts, gamma, beta, out);
    }
}

// Round 10
// 73.015 us; speedup vs baseline: 1.0008x; 1.0008x over previous
//
#include <hip/hip_runtime.h>

#define HW        128
#define PLANE     16384            // 128*128
#define NCH       64
#define NB        32
#define NQ        4
#define NPART     8192             // fallback partial count
#define COUNT_INV (1.0f / 524288.0f)
#define EPSV      1e-5f
#define GRID_C    1024             // coop grid: 1024 blocks x 2 planes

#define YELEMS    (NB * NCH * PLANE)
#define PART_OFF  (YELEMS / 2)
#define WS_NEED   ((size_t)YELEMS * 2 + 16384 * 4)

typedef float    f4v __attribute__((ext_vector_type(4)));
typedef _Float16 h4v __attribute__((ext_vector_type(4)));

// 6-row x 6-col window; horizontal halo via cross-lane shuffle (1 float4 load
// per row instead of 1 float4 + 2 edge dwords). Lane layout: lane = (rg&1)*32+cg,
// so shfl_up(1)/shfl_down(1) cross cg groups only at cg==0/31, which are masked
// to the zero-pad value anyway.
__device__ __forceinline__ void load_win(const float* __restrict__ bp, int r0, int w4,
                                         bool hasL, bool hasR, float (&v)[6][6]) {
#pragma unroll
    for (int i = 0; i < 6; ++i) {
        int g = r0 - 1 + i;
        float4 m = make_float4(0.f, 0.f, 0.f, 0.f);
        if ((unsigned)g < (unsigned)HW)
            m = *(const float4*)(bp + g * HW + w4);
        float l = __shfl_up(m.w, 1);
        float r = __shfl_down(m.x, 1);
        v[i][0] = hasL ? l : 0.f;
        v[i][1] = m.x; v[i][2] = m.y; v[i][3] = m.z; v[i][4] = m.w;
        v[i][5] = hasR ? r : 0.f;
    }
}

__device__ __forceinline__ void conv_row(const float (&tp)[6], const float (&md)[6],
                                         const float (&bt)[6], const float* W,
                                         float bias, float (&acc)[4]) {
#pragma unroll
    for (int j = 0; j < 4; ++j) {
        float a = bias;
        a = fmaf(tp[j],     W[0], a);
        a = fmaf(tp[j + 1], W[1], a);
        a = fmaf(tp[j + 2], W[2], a);
        a = fmaf(md[j],     W[3], a);
        a = fmaf(md[j + 1], W[4], a);
        a = fmaf(md[j + 2], W[5], a);
        a = fmaf(bt[j],     W[6], a);
        a = fmaf(bt[j + 1], W[7], a);
        a = fmaf(bt[j + 2], W[8], a);
        acc[j] = a;
    }
}

// ---------------- fused coop kernel: recompute conv, inline barrier ----------------
// 1024 blocks x 256 threads, planes 2b and 2b+1 per block. Phase 1: conv+stats
// (x pulled from HBM -> lands in L3). Barrier. Fold (per-block channels).
// Phase 2: recompute conv (x re-read L3-served, proven by round-3 FETCH=138MB),
// normalize+relu, nontemporal store. Nothing big lives across the barrier.
// ws floats: [0..2047] per-plane sum (idx c*32+n), [2048..4095] sumsq,
//            [4096] arrival counter (zeroed via hipMemsetAsync each launch).
__global__ __launch_bounds__(256, 4) void fused(const float* __restrict__ x,
                                                const float* __restrict__ wgt,
                                                const float* __restrict__ bias,
                                                const float* __restrict__ gamma,
                                                const float* __restrict__ beta,
                                                float* __restrict__ partials,
                                                unsigned int* __restrict__ cnt,
                                                float* __restrict__ out) {
    __shared__ float red[8];
    __shared__ float ssh[4];           // {s,sh} for plane pp=0,1
    const int b   = blockIdx.x;        // 0..1023
    const int t   = threadIdx.x;
    const int cg_ = t & 31, rg = t >> 5;
    const int w4  = cg_ * 4;
    const bool hasL = (cg_ != 0), hasR = (cg_ != 31);

    // ---- phase 1: conv + per-plane stats for planes 2b, 2b+1 ----
#pragma unroll
    for (int pp = 0; pp < 2; ++pp) {
        const int plane = b * 2 + pp;
        const int c = plane & 63, n = plane >> 6;
        const float* bp = x + (size_t)plane * PLANE;

        float W[9];
#pragma unroll
        for (int k = 0; k < 9; ++k) W[k] = wgt[c * 9 + k];
        const float bv = bias[c];

        float sum = 0.f, sq = 0.f;
#pragma unroll
        for (int q = 0; q < 4; ++q) {
            const int r0 = q * 32 + rg * 4;
            float v[6][6];
            load_win(bp, r0, w4, hasL, hasR, v);
#pragma unroll
            for (int k = 0; k < 4; ++k) {
                float acc[4];
                conv_row(v[k], v[k + 1], v[k + 2], W, bv, acc);
#pragma unroll
                for (int j = 0; j < 4; ++j) {
                    sum += acc[j];
                    sq = fmaf(acc[j], acc[j], sq);
                }
            }
        }
#pragma unroll
        for (int off = 32; off; off >>= 1) {
            sum += __shfl_down(sum, off);
            sq  += __shfl_down(sq, off);
        }
        if ((t & 63) == 0) { red[t >> 6] = sum; red[4 + (t >> 6)] = sq; }
        __syncthreads();
        if (t == 0) {
            partials[c * 32 + n]        = red[0] + red[1] + red[2] + red[3];
            partials[2048 + c * 32 + n] = red[4] + red[5] + red[6] + red[7];
        }
        __syncthreads();
    }

    // ---- inline grid barrier (proven round 9: passes capture + coherence) ----
    if (t == 0) {
        __threadfence();
        __hip_atomic_fetch_add(cnt, 1u, __ATOMIC_ACQ_REL, __HIP_MEMORY_SCOPE_AGENT);
        while (__hip_atomic_load(cnt, __ATOMIC_ACQUIRE, __HIP_MEMORY_SCOPE_AGENT)
               < (unsigned)GRID_C) {
            __builtin_amdgcn_s_sleep(8);
        }
    }
    __syncthreads();

    // ---- stats fold: wave0 folds plane0's channel, wave1 folds plane1's ----
    {
        const int c0 = (b * 2) & 63;
        const int c1 = (b * 2 + 1) & 63;
        if (t < 32) {
            float S = partials[c0 * 32 + t];
            float Q = partials[2048 + c0 * 32 + t];
#pragma unroll
            for (int off = 16; off; off >>= 1) {
                S += __shfl_xor(S, off);
                Q += __shfl_xor(Q, off);
            }
            if (t == 0) {
                float mean = S * COUNT_INV;
                float var  = fmaxf(Q * COUNT_INV - mean * mean, 0.f);
                float s    = gamma[c0] * rsqrtf(var + EPSV);
                ssh[0] = s;
                ssh[1] = beta[c0] - mean * s;
            }
        } else if (t >= 64 && t < 96) {
            const int l = t - 64;
            float S = partials[c1 * 32 + l];
            float Q = partials[2048 + c1 * 32 + l];
#pragma unroll
            for (int off = 16; off; off >>= 1) {
                S += __shfl_xor(S, off);
                Q += __shfl_xor(Q, off);
            }
            if (l == 0) {
                float mean = S * COUNT_INV;
                float var  = fmaxf(Q * COUNT_INV - mean * mean, 0.f);
                float s    = gamma[c1] * rsqrtf(var + EPSV);
                ssh[2] = s;
                ssh[3] = beta[c1] - mean * s;
            }
        }
    }
    __syncthreads();

    // ---- phase 2: recompute conv (x from L3), normalize, relu, store ----
#pragma unroll
    for (int pp = 0; pp < 2; ++pp) {
        const int plane = b * 2 + pp;
        const int c = plane & 63;
        const float* bp = x + (size_t)plane * PLANE;
        float* op = out + (size_t)plane * PLANE;

        float W[9];
#pragma unroll
        for (int k = 0; k < 9; ++k) W[k] = wgt[c * 9 + k];
        const float s  = ssh[pp * 2];
        const float sh = fmaf(bias[c], s, ssh[pp * 2 + 1]);

#pragma unroll
        for (int q = 0; q < 4; ++q) {
            const int r0 = q * 32 + rg * 4;
            float v[6][6];
            load_win(bp, r0, w4, hasL, hasR, v);
#pragma unroll
            for (int k = 0; k < 4; ++k) {
                float acc[4];
                conv_row(v[k], v[k + 1], v[k + 2], W, 0.f, acc);
                f4v o;
                o.x = fmaxf(fmaf(acc[0], s, sh), 0.f);
                o.y = fmaxf(fmaf(acc[1], s, sh), 0.f);
                o.z = fmaxf(fmaf(acc[2], s, sh), 0.f);
                o.w = fmaxf(fmaf(acc[3], s, sh), 0.f);
                __builtin_nontemporal_store(o, (f4v*)(op + (r0 + k) * HW + w4));
            }
        }
    }
}

// ---------------- fallback: round-5 two-pass (fp16 y staging, proven 73 us) ----------------
__device__ __forceinline__ void load_win_fb(const float* __restrict__ bp, int r0, int w4,
                                            bool hasL, bool hasR, float (&v)[6][6]) {
#pragma unroll
    for (int i = 0; i < 6; ++i) {
        int g = r0 - 1 + i;
        if ((unsigned)g < (unsigned)HW) {
            const float* rp = bp + g * HW + w4;
            float4 m = *(const float4*)rp;
            v[i][0] = hasL ? rp[-1] : 0.f;
            v[i][1] = m.x; v[i][2] = m.y; v[i][3] = m.z; v[i][4] = m.w;
            v[i][5] = hasR ? rp[4] : 0.f;
        } else {
#pragma unroll
            for (int j = 0; j < 6; ++j) v[i][j] = 0.f;
        }
    }
}

__global__ __launch_bounds__(256) void pass_conv_stats(const float* __restrict__ x,
                                                       const float* __restrict__ wgt,
                                                       const float* __restrict__ bias,
                                                       _Float16* __restrict__ yh,
                                                       float* __restrict__ partials) {
    __shared__ float red[8];
    const int bid   = blockIdx.x;
    const int q     = bid & 3;
    const int plane = bid >> 2;
    const int c     = plane & 63;
    const int n     = plane >> 6;
    const int t     = threadIdx.x;
    const int cg    = t & 31, rg = t >> 5;
    const int w4    = cg * 4, r0 = q * 32 + rg * 4;
    const bool hasL = (cg != 0), hasR = (cg != 31);

    float W[9];
#pragma unroll
    for (int k = 0; k < 9; ++k) W[k] = wgt[c * 9 + k];
    const float bv = bias[c];
    const float* bp = x + (size_t)plane * PLANE;
    _Float16* yp = yh + (size_t)plane * PLANE;

    float v[6][6];
    load_win_fb(bp, r0, w4, hasL, hasR, v);

    float sum = 0.f, sq = 0.f;
#pragma unroll
    for (int k = 0; k < 4; ++k) {
        float acc[4];
        conv_row(v[k], v[k + 1], v[k + 2], W, bv, acc);
        h4v hv;
        hv.x = (_Float16)acc[0]; hv.y = (_Float16)acc[1];
        hv.z = (_Float16)acc[2]; hv.w = (_Float16)acc[3];
        *(h4v*)(yp + (r0 + k) * HW + w4) = hv;
#pragma unroll
        for (int j = 0; j < 4; ++j) { sum += acc[j]; sq = fmaf(acc[j], acc[j], sq); }
    }
#pragma unroll
    for (int off = 32; off; off >>= 1) {
        sum += __shfl_down(sum, off);
        sq  += __shfl_down(sq, off);
    }
    const int wave = t >> 6, lane = t & 63;
    if (lane == 0) { red[wave] = sum; red[4 + wave] = sq; }
    __syncthreads();
    if (t == 0) {
        const int pi = n * 4 + q;
        partials[c * 128 + pi]         = red[0] + red[1] + red[2] + red[3];
        partials[NPART + c * 128 + pi] = red[4] + red[5] + red[6] + red[7];
    }
}

__global__ __launch_bounds__(256) void pass_norm(const _Float16* __restrict__ yh,
                                                 const float* __restrict__ partials,
                                                 const float* __restrict__ gamma,
                                                 const float* __restrict__ beta,
                                                 float* __restrict__ out) {
    const int bid   = blockIdx.x;
    const int q     = bid & 3;
    const int plane = bid >> 2;
    const int c     = plane & 63;
    const int t     = threadIdx.x;
    const int cg    = t & 31, rg = t >> 5;
    const int w4    = cg * 4, r0 = q * 32 + rg * 4;

    const _Float16* yp = yh + (size_t)plane * PLANE;
    h4v hv[4];
#pragma unroll
    for (int k = 0; k < 4; ++k)
        hv[k] = *(const h4v*)(yp + (r0 + k) * HW + w4);

    const int lane = t & 63;
    float S = partials[c * 128 + lane]         + partials[c * 128 + 64 + lane];
    float Q = partials[NPART + c * 128 + lane] + partials[NPART + c * 128 + 64 + lane];
#pragma unroll
    for (int off = 32; off; off >>= 1) {
        S += __shfl_xor(S, off);
        Q += __shfl_xor(Q, off);
    }
    const float mean = S * COUNT_INV;
    const float var  = fmaxf(Q * COUNT_INV - mean * mean, 0.f);
    const float s    = gamma[c] * rsqrtf(var + EPSV);
    const float sh   = beta[c] - mean * s;

    float* op = out + (size_t)plane * PLANE;
#pragma unroll
    for (int k = 0; k < 4; ++k) {
        f4v o;
        o.x = fmaxf(fmaf((float)hv[k].x, s, sh), 0.f);
        o.y = fmaxf(fmaf((float)hv[k].y, s, sh), 0.f);
        o.z = fmaxf(fmaf((float)hv[k].z, s, sh), 0.f);
        o.w = fmaxf(fmaf((float)hv[k].w, s, sh), 0.f);
        __builtin_nontemporal_store(o, (f4v*)(op + (r0 + k) * HW + w4));
    }
}

extern "C" void kernel_launch(void* const* d_in, const int* in_sizes, int n_in,
                              void* d_out, int out_size, void* d_ws, size_t ws_size,
                              hipStream_t stream) {
    const float* x     = (const float*)d_in[0];
    const float* w     = (const float*)d_in[1];
    const float* b     = (const float*)d_in[2];
    const float* gamma = (const float*)d_in[3];
    const float* beta  = (const float*)d_in[4];
    float* out = (float*)d_out;

    int nb = 0;
    hipError_t qe = hipOccupancyMaxActiveBlocksPerMultiprocessor(
        &nb, reinterpret_cast<const void*>(fused), 256, 0);

    bool coop_ok = false;
    if (qe == hipSuccess && nb >= 4) {
        float* parts      = (float*)d_ws;
        unsigned int* cnt = (unsigned int*)((float*)d_ws + 4096);
        hipMemsetAsync(cnt, 0, sizeof(unsigned int), stream);
        const float* xa = x; const float* wa = w; const float* ba = b;
        const float* ga = gamma; const float* be = beta;
        float* pw = parts; unsigned int* ca = cnt; float* oa = out;
        void* args[] = {&xa, &wa, &ba, &ga, &be, &pw, &ca, &oa};
        hipError_t le = hipLaunchCooperativeKernel(
            reinterpret_cast<const void*>(fused), dim3(GRID_C), dim3(256),
            args, 0, stream);
        coop_ok = (le == hipSuccess);
    }

    if (!coop_ok && ws_size >= WS_NEED) {
        _Float16* yh  = (_Float16*)d_ws;
        float* parts  = (float*)d_ws + PART_OFF;
        pass_conv_stats<<<NB * NCH * NQ, 256, 0, stream>>>(x, w, b, yh, parts);
        pass_norm<<<NB * NCH * NQ, 256, 0, stream>>>(yh, parts, gamma, beta, out);
    }
}

// Round 11
// 72.812 us; speedup vs baseline: 1.0036x; 1.0028x over previous
//
#include <hip/hip_runtime.h>

#define HW        128
#define PLANE     16384            // 128*128
#define NCH       64
#define NB        32
#define NQ        4
#define NPART     8192             // fallback partial count
#define COUNT_INV (1.0f / 524288.0f)
#define EPSV      1e-5f
#define GRID_C    1024             // coop grid: planes b and b+1024 per block

#define YELEMS    (NB * NCH * PLANE)
#define PART_OFF  (YELEMS / 2)
#define WS_NEED   ((size_t)YELEMS * 2 + 16384 * 4)

typedef float    f4v __attribute__((ext_vector_type(4)));
typedef _Float16 h2v __attribute__((ext_vector_type(2)));
typedef _Float16 h4v __attribute__((ext_vector_type(4)));
typedef _Float16 h8v __attribute__((ext_vector_type(8)));

__device__ __forceinline__ void load_win(const float* __restrict__ bp, int r0, int w4,
                                         bool hasL, bool hasR, float (&v)[6][6]) {
#pragma unroll
    for (int i = 0; i < 6; ++i) {
        int g = r0 - 1 + i;
        if ((unsigned)g < (unsigned)HW) {
            const float* rp = bp + g * HW + w4;
            float4 m = *(const float4*)rp;
            v[i][0] = hasL ? rp[-1] : 0.f;
            v[i][1] = m.x; v[i][2] = m.y; v[i][3] = m.z; v[i][4] = m.w;
            v[i][5] = hasR ? rp[4] : 0.f;
        } else {
#pragma unroll
            for (int j = 0; j < 6; ++j) v[i][j] = 0.f;
        }
    }
}

__device__ __forceinline__ void conv_row(const float (&tp)[6], const float (&md)[6],
                                         const float (&bt)[6], const float* W,
                                         float bias, float (&acc)[4]) {
#pragma unroll
    for (int j = 0; j < 4; ++j) {
        float a = bias;
        a = fmaf(tp[j],     W[0], a);
        a = fmaf(tp[j + 1], W[1], a);
        a = fmaf(tp[j + 2], W[2], a);
        a = fmaf(md[j],     W[3], a);
        a = fmaf(md[j + 1], W[4], a);
        a = fmaf(md[j + 2], W[5], a);
        a = fmaf(bt[j],     W[6], a);
        a = fmaf(bt[j + 1], W[7], a);
        a = fmaf(bt[j + 2], W[8], a);
        acc[j] = a;
    }
}

// ---- plane-B (register y) helpers: manual unroll, all vector indices literal ----
#define SUMACC(acc)                                                            \
    { sum += acc[0] + acc[1] + acc[2] + acc[3];                                \
      sq = fmaf(acc[0], acc[0], sq); sq = fmaf(acc[1], acc[1], sq);            \
      sq = fmaf(acc[2], acc[2], sq); sq = fmaf(acc[3], acc[3], sq); }

#define PH1B(Q, YA, YB_)                                                       \
    {                                                                          \
        const int r0 = (Q) * 32 + rg * 4;                                      \
        float v[6][6];                                                         \
        load_win(bpB, r0, w4, hasL, hasR, v);                                  \
        float acc[4];                                                          \
        conv_row(v[0], v[1], v[2], W, bv, acc);                                \
        YA[0] = (_Float16)acc[0]; YA[1] = (_Float16)acc[1];                    \
        YA[2] = (_Float16)acc[2]; YA[3] = (_Float16)acc[3];                    \
        SUMACC(acc)                                                            \
        conv_row(v[1], v[2], v[3], W, bv, acc);                                \
        YA[4] = (_Float16)acc[0]; YA[5] = (_Float16)acc[1];                    \
        YA[6] = (_Float16)acc[2]; YA[7] = (_Float16)acc[3];                    \
        SUMACC(acc)                                                            \
        conv_row(v[2], v[3], v[4], W, bv, acc);                                \
        YB_[0] = (_Float16)acc[0]; YB_[1] = (_Float16)acc[1];                  \
        YB_[2] = (_Float16)acc[2]; YB_[3] = (_Float16)acc[3];                  \
        SUMACC(acc)                                                            \
        conv_row(v[3], v[4], v[5], W, bv, acc);                                \
        YB_[4] = (_Float16)acc[0]; YB_[5] = (_Float16)acc[1];                  \
        YB_[6] = (_Float16)acc[2]; YB_[7] = (_Float16)acc[3];                  \
        SUMACC(acc)                                                            \
    }

#define PH2B(Q, YA, YB_)                                                       \
    {                                                                          \
        const int r0 = (Q) * 32 + rg * 4;                                      \
        f4v o;                                                                 \
        o.x = fmaxf(fmaf((float)YA[0], s, sh), 0.f);                           \
        o.y = fmaxf(fmaf((float)YA[1], s, sh), 0.f);                           \
        o.z = fmaxf(fmaf((float)YA[2], s, sh), 0.f);                           \
        o.w = fmaxf(fmaf((float)YA[3], s, sh), 0.f);                           \
        __builtin_nontemporal_store(o, (f4v*)(opB + (r0 + 0) * HW + w4));      \
        o.x = fmaxf(fmaf((float)YA[4], s, sh), 0.f);                           \
        o.y = fmaxf(fmaf((float)YA[5], s, sh), 0.f);                           \
        o.z = fmaxf(fmaf((float)YA[6], s, sh), 0.f);                           \
        o.w = fmaxf(fmaf((float)YA[7], s, sh), 0.f);                           \
        __builtin_nontemporal_store(o, (f4v*)(opB + (r0 + 1) * HW + w4));      \
        o.x = fmaxf(fmaf((float)YB_[0], s, sh), 0.f);                          \
        o.y = fmaxf(fmaf((float)YB_[1], s, sh), 0.f);                          \
        o.z = fmaxf(fmaf((float)YB_[2], s, sh), 0.f);                          \
        o.w = fmaxf(fmaf((float)YB_[3], s, sh), 0.f);                          \
        __builtin_nontemporal_store(o, (f4v*)(opB + (r0 + 2) * HW + w4));      \
        o.x = fmaxf(fmaf((float)YB_[4], s, sh), 0.f);                          \
        o.y = fmaxf(fmaf((float)YB_[5], s, sh), 0.f);                          \
        o.z = fmaxf(fmaf((float)YB_[6], s, sh), 0.f);                          \
        o.w = fmaxf(fmaf((float)YB_[7], s, sh), 0.f);                          \
        __builtin_nontemporal_store(o, (f4v*)(opB + (r0 + 3) * HW + w4));      \
    }

// ---------------- fused coop kernel: y on-chip (LDS + regs), 269 MB fabric ----------
// 1024 blocks x 256 threads, 4 blocks/CU. Block b: plane A = b (y -> 32 KB LDS),
// plane B = b+1024 (y -> 8 named h8v = 32 VGPR). Same channel c = b&63 for both.
// Phase 2 never re-reads x. ws floats: [0..2047] per-plane sum (idx c*32+n),
// [2048..4095] sumsq, [4096] arrival counter (hipMemsetAsync'd to 0 each launch).
__global__ __launch_bounds__(256, 4) void fused(const float* __restrict__ x,
                                                const float* __restrict__ wgt,
                                                const float* __restrict__ bias,
                                                const float* __restrict__ gamma,
                                                const float* __restrict__ beta,
                                                float* __restrict__ partials,
                                                unsigned int* __restrict__ cnt,
                                                float* __restrict__ out) {
    __shared__ unsigned int ylds[32 * 256];   // plane-A y, fp16x2, [word][tid]
    __shared__ float red[8];
    __shared__ float ssh[2];
    const int b   = blockIdx.x;        // 0..1023
    const int c   = b & 63;
    const int nA  = b >> 6;            // 0..15
    const int t   = threadIdx.x;
    const int cg_ = t & 31, rg = t >> 5;
    const int w4  = cg_ * 4;
    const bool hasL = (cg_ != 0), hasR = (cg_ != 31);

    float W[9];
#pragma unroll
    for (int k = 0; k < 9; ++k) W[k] = wgt[c * 9 + k];
    const float bv = bias[c];

    // ---- phase 1A: plane b -> y in LDS + stats ----
    {
        const float* bp = x + (size_t)b * PLANE;
        float sum = 0.f, sq = 0.f;
#pragma unroll
        for (int q = 0; q < 4; ++q) {
            const int r0 = q * 32 + rg * 4;
            float v[6][6];
            load_win(bp, r0, w4, hasL, hasR, v);
#pragma unroll
            for (int k = 0; k < 4; ++k) {
                float acc[4];
                conv_row(v[k], v[k + 1], v[k + 2], W, bv, acc);
                h2v p0, p1;
                p0.x = (_Float16)acc[0]; p0.y = (_Float16)acc[1];
                p1.x = (_Float16)acc[2]; p1.y = (_Float16)acc[3];
                ylds[(q * 8 + k * 2) * 256 + t]     = __builtin_bit_cast(unsigned int, p0);
                ylds[(q * 8 + k * 2 + 1) * 256 + t] = __builtin_bit_cast(unsigned int, p1);
                SUMACC(acc)
            }
        }
#pragma unroll
        for (int off = 32; off; off >>= 1) {
            sum += __shfl_down(sum, off);
            sq  += __shfl_down(sq, off);
        }
        if ((t & 63) == 0) { red[t >> 6] = sum; red[4 + (t >> 6)] = sq; }
        __syncthreads();
        if (t == 0) {
            partials[c * 32 + nA]        = red[0] + red[1] + red[2] + red[3];
            partials[2048 + c * 32 + nA] = red[4] + red[5] + red[6] + red[7];
        }
        __syncthreads();
    }

    // ---- phase 1B: plane b+1024 -> y in 8 named h8v regs + stats ----
    h8v y0, y1, y2, y3, y4, y5, y6, y7;
    {
        const float* bpB = x + (size_t)(b + 1024) * PLANE;
        float sum = 0.f, sq = 0.f;
        PH1B(0, y0, y1)
        PH1B(1, y2, y3)
        PH1B(2, y4, y5)
        PH1B(3, y6, y7)
#pragma unroll
        for (int off = 32; off; off >>= 1) {
            sum += __shfl_down(sum, off);
            sq  += __shfl_down(sq, off);
        }
        if ((t & 63) == 0) { red[t >> 6] = sum; red[4 + (t >> 6)] = sq; }
        __syncthreads();
        if (t == 0) {
            partials[c * 32 + nA + 16]        = red[0] + red[1] + red[2] + red[3];
            partials[2048 + c * 32 + nA + 16] = red[4] + red[5] + red[6] + red[7];
        }
        __syncthreads();
    }

    // ---- inline grid barrier (R9/R10-proven) ----
    if (t == 0) {
        __threadfence();
        __hip_atomic_fetch_add(cnt, 1u, __ATOMIC_ACQ_REL, __HIP_MEMORY_SCOPE_AGENT);
        while (__hip_atomic_load(cnt, __ATOMIC_ACQUIRE, __HIP_MEMORY_SCOPE_AGENT)
               < (unsigned)GRID_C) {
            __builtin_amdgcn_s_sleep(8);
        }
    }
    __syncthreads();

    // ---- stats fold: 32 lanes, channel c ----
    if (t < 32) {
        float S = partials[c * 32 + t];
        float Q = partials[2048 + c * 32 + t];
#pragma unroll
        for (int off = 16; off; off >>= 1) {
            S += __shfl_xor(S, off);
            Q += __shfl_xor(Q, off);
        }
        if (t == 0) {
            float mean = S * COUNT_INV;
            float var  = fmaxf(Q * COUNT_INV - mean * mean, 0.f);
            float s    = gamma[c] * rsqrtf(var + EPSV);
            ssh[0] = s;
            ssh[1] = beta[c] - mean * s;   // conv bias already inside y
        }
    }
    __syncthreads();
    const float s  = ssh[0];
    const float sh = ssh[1];

    // ---- phase 2A: plane b from LDS ----
    {
        float* op = out + (size_t)b * PLANE;
#pragma unroll
        for (int q = 0; q < 4; ++q) {
#pragma unroll
            for (int k = 0; k < 4; ++k) {
                h2v p0 = __builtin_bit_cast(h2v, ylds[(q * 8 + k * 2) * 256 + t]);
                h2v p1 = __builtin_bit_cast(h2v, ylds[(q * 8 + k * 2 + 1) * 256 + t]);
                f4v o;
                o.x = fmaxf(fmaf((float)p0.x, s, sh), 0.f);
                o.y = fmaxf(fmaf((float)p0.y, s, sh), 0.f);
                o.z = fmaxf(fmaf((float)p1.x, s, sh), 0.f);
                o.w = fmaxf(fmaf((float)p1.y, s, sh), 0.f);
                const int row = q * 32 + rg * 4 + k;
                __builtin_nontemporal_store(o, (f4v*)(op + row * HW + w4));
            }
        }
    }

    // ---- phase 2B: plane b+1024 from regs ----
    {
        float* opB = out + (size_t)(b + 1024) * PLANE;
        PH2B(0, y0, y1)
        PH2B(1, y2, y3)
        PH2B(2, y4, y5)
        PH2B(3, y6, y7)
    }
}

// ---------------- fallback: round-5 two-pass (fp16 y staging, proven 73 us) ----------------
__global__ __launch_bounds__(256) void pass_conv_stats(const float* __restrict__ x,
                                                       const float* __restrict__ wgt,
                                                       const float* __restrict__ bias,
                                                       _Float16* __restrict__ yh,
                                                       float* __restrict__ partials) {
    __shared__ float red[8];
    const int bid   = blockIdx.x;
    const int q     = bid & 3;
    const int plane = bid >> 2;
    const int c     = plane & 63;
    const int n     = plane >> 6;
    const int t     = threadIdx.x;
    const int cg    = t & 31, rg = t >> 5;
    const int w4    = cg * 4, r0 = q * 32 + rg * 4;
    const bool hasL = (cg != 0), hasR = (cg != 31);

    float W[9];
#pragma unroll
    for (int k = 0; k < 9; ++k) W[k] = wgt[c * 9 + k];
    const float bv = bias[c];
    const float* bp = x + (size_t)plane * PLANE;
    _Float16* yp = yh + (size_t)plane * PLANE;

    float v[6][6];
    load_win(bp, r0, w4, hasL, hasR, v);

    float sum = 0.f, sq = 0.f;
#pragma unroll
    for (int k = 0; k < 4; ++k) {
        float acc[4];
        conv_row(v[k], v[k + 1], v[k + 2], W, bv, acc);
        h4v hv;
        hv.x = (_Float16)acc[0]; hv.y = (_Float16)acc[1];
        hv.z = (_Float16)acc[2]; hv.w = (_Float16)acc[3];
        *(h4v*)(yp + (r0 + k) * HW + w4) = hv;
        SUMACC(acc)
    }
#pragma unroll
    for (int off = 32; off; off >>= 1) {
        sum += __shfl_down(sum, off);
        sq  += __shfl_down(sq, off);
    }
    const int wave = t >> 6, lane = t & 63;
    if (lane == 0) { red[wave] = sum; red[4 + wave] = sq; }
    __syncthreads();
    if (t == 0) {
        const int pi = n * 4 + q;
        partials[c * 128 + pi]         = red[0] + red[1] + red[2] + red[3];
        partials[NPART + c * 128 + pi] = red[4] + red[5] + red[6] + red[7];
    }
}

__global__ __launch_bounds__(256) void pass_norm(const _Float16* __restrict__ yh,
                                                 const float* __restrict__ partials,
                                                 const float* __restrict__ gamma,
                                                 const float* __restrict__ beta,
                                                 float* __restrict__ out) {
    const int bid   = blockIdx.x;
    const int q     = bid & 3;
    const int plane = bid >> 2;
    const int c     = plane & 63;
    const int t     = threadIdx.x;
    const int cg    = t & 31, rg = t >> 5;
    const int w4    = cg * 4, r0 = q * 32 + rg * 4;

    const _Float16* yp = yh + (size_t)plane * PLANE;
    h4v hv[4];
#pragma unroll
    for (int k = 0; k < 4; ++k)
        hv[k] = *(const h4v*)(yp + (r0 + k) * HW + w4);

    const int lane = t & 63;
    float S = partials[c * 128 + lane]         + partials[c * 128 + 64 + lane];
    float Q = partials[NPART + c * 128 + lane] + partials[NPART + c * 128 + 64 + lane];
#pragma unroll
    for (int off = 32; off; off >>= 1) {
        S += __shfl_xor(S, off);
        Q += __shfl_xor(Q, off);
    }
    const float mean = S * COUNT_INV;
    const float var  = fmaxf(Q * COUNT_INV - mean * mean, 0.f);
    const float s    = gamma[c] * rsqrtf(var + EPSV);
    const float sh   = beta[c] - mean * s;

    float* op = out + (size_t)plane * PLANE;
#pragma unroll
    for (int k = 0; k < 4; ++k) {
        f4v o;
        o.x = fmaxf(fmaf((float)hv[k].x, s, sh), 0.f);
        o.y = fmaxf(fmaf((float)hv[k].y, s, sh), 0.f);
        o.z = fmaxf(fmaf((float)hv[k].z, s, sh), 0.f);
        o.w = fmaxf(fmaf((float)hv[k].w, s, sh), 0.f);
        __builtin_nontemporal_store(o, (f4v*)(op + (r0 + k) * HW + w4));
    }
}

extern "C" void kernel_launch(void* const* d_in, const int* in_sizes, int n_in,
                              void* d_out, int out_size, void* d_ws, size_t ws_size,
                              hipStream_t stream) {
    const float* x     = (const float*)d_in[0];
    const float* w     = (const float*)d_in[1];
    const float* b     = (const float*)d_in[2];
    const float* gamma = (const float*)d_in[3];
    const float* beta  = (const float*)d_in[4];
    float* out = (float*)d_out;

    int nb = 0;
    hipError_t qe = hipOccupancyMaxActiveBlocksPerMultiprocessor(
        &nb, reinterpret_cast<const void*>(fused), 256, 0);

    bool coop_ok = false;
    if (qe == hipSuccess && nb >= 4) {
        float* parts      = (float*)d_ws;
        unsigned int* cnt = (unsigned int*)((float*)d_ws + 4096);
        hipMemsetAsync(cnt, 0, sizeof(unsigned int), stream);
        const float* xa = x; const float* wa = w; const float* ba = b;
        const float* ga = gamma; const float* be = beta;
        float* pw = parts; unsigned int* ca = cnt; float* oa = out;
        void* args[] = {&xa, &wa, &ba, &ga, &be, &pw, &ca, &oa};
        hipError_t le = hipLaunchCooperativeKernel(
            reinterpret_cast<const void*>(fused), dim3(GRID_C), dim3(256),
            args, 0, stream);
        coop_ok = (le == hipSuccess);
    }

    if (!coop_ok && ws_size >= WS_NEED) {
        _Float16* yh  = (_Float16*)d_ws;
        float* parts  = (float*)d_ws + PART_OFF;
        pass_conv_stats<<<NB * NCH * NQ, 256, 0, stream>>>(x, w, b, yh, parts);
        pass_norm<<<NB * NCH * NQ, 256, 0, stream>>>(yh, parts, gamma, beta, out);
    }
}